// Round 14
// baseline (103.970 us; speedup 1.0000x reference)
//
#include <hip/hip_runtime.h>
#include <hip/hip_bf16.h>

typedef _Float16 half2v __attribute__((ext_vector_type(2)));

constexpr int kHD  = 10;
constexpr int kP   = 6;
constexpr int kNE  = 5;
constexpr int kH   = 128;
constexpr int kHin = 64;
constexpr int kSeg = 70;    // 60 xh row-segments + 10 xf row-segments
constexpr int kSegPad = 72; // pad to multiple of 4 for 16B DMA groups

// packed-weight layout in d_ws (half2 pairs)
constexpr int WF2  = 0;     // 60  : Wf  [p][20]
constexpr int WH2  = 60;    // 60  : Wh  [p][20]
constexpr int WATT2= 120;   // 30  : Watt[p][10]
constexpr int WDP2 = 150;   // 500 : Wdp [e][10][20]
constexpr int WUP2 = 650;   // 1200: Wup [p][10][40]
constexpr int NPAIR= 1850;

__device__ __forceinline__ float sigm(float v) {
    return 1.0f / (1.0f + __expf(-v));
}
__device__ __forceinline__ half2v pk(float a, float b) {
    half2v h; h[0] = (_Float16)a; h[1] = (_Float16)b; return h;
}
__device__ __forceinline__ float dot2(half2v a, half2v b, float c) {
    return __builtin_amdgcn_fdot2(a, b, c, false);
}

__global__ __launch_bounds__(256)
void prepack_weights(const float* __restrict__ Wf,  const float* __restrict__ Wh,
                     const float* __restrict__ Watt, const float* __restrict__ Wdp,
                     const float* __restrict__ Wup, half2v* __restrict__ out)
{
    const int i = blockIdx.x * 256 + threadIdx.x;
    if (i >= NPAIR) return;
    const float* src; int k;
    if      (i < WH2)   { src = Wf;   k = i; }
    else if (i < WATT2) { src = Wh;   k = i - WH2; }
    else if (i < WDP2)  { src = Watt; k = i - WATT2; }
    else if (i < WUP2)  { src = Wdp;  k = i - WDP2; }
    else                { src = Wup;  k = i - WUP2; }
    out[i] = pk(src[2 * k], src[2 * k + 1]);
}

// R13 (97.4us) + ALL bulk input traffic via global_load_lds DMA:
//  - xh/xf staging DMA (18 issues/wave) AND the 60-plane xp tile DMA
//    (15 issues/wave, 1KB per plane = two contiguous rows) fly concurrently,
//    drained by ONE barrier. Zero VMEM waits in the compute tail; xp reads
//    become stride-1 LDS reads. No dest-VGPR pressure.
__global__ __launch_bounds__(256, 2)
void Part_Graph_51539607552364_kernel(
    const float* __restrict__ xf,  const float* __restrict__ xh0,
    const float* __restrict__ xh1, const float* __restrict__ xp,
    const half2v* __restrict__ w2,
    const float* __restrict__ bfb, const float* __restrict__ bhb,
    const float* __restrict__ batt,
    float* __restrict__ out_xp,
    float* __restrict__ out_att)
{
    __shared__ float stage[kSegPad * kHin];   // 18432 B
    __shared__ float xpl[kP * kHD * 256];     // 61440 B   (total 79872 B)

    const int bid = blockIdx.x;
    const int n   = bid >> 6;           // 64 blocks per image
    const int R   = bid & 63;           // row-pair index; rows yA=2R, yA+1
    const int yA  = R * 2;

    const float scale = 63.0f / 127.0f;
    int ry0 = (int)((float)yA * scale);
    ry0 = ry0 > (kHin - 2) ? (kHin - 2) : ry0;

    const int wv = threadIdx.x >> 6;
    const int l  = threadIdx.x & 63;

    // ---- PHASE 1a: DMA xh/xf stage (groups of 4 segments, 16B/lane) ----
    for (int g = wv; g < kSegPad / 4; g += 4) {
        int seg = g * 4 + (l >> 4);
        if (seg > kSeg - 1) seg = kSeg - 1;            // pad lanes clamp
        const int col4 = (l & 15) * 4;
        const float* rowp;
        if (seg < 60) {
            const int map = seg / 30, rem = seg % 30;
            const int ch = rem / 3, r3 = rem % 3;
            int srow = ry0 + r3;
            srow = srow > (kHin - 1) ? (kHin - 1) : srow;
            rowp = (map ? xh1 : xh0) +
                   ((size_t)(n * kHD + ch) * kHin + srow) * kHin;
        } else {
            const int ch = seg - 60;
            rowp = xf + ((size_t)(n * kHD + ch) * kHin + R) * kHin;
        }
        __builtin_amdgcn_global_load_lds(
            (const __attribute__((address_space(1))) void*)(rowp + col4),
            (__attribute__((address_space(3))) void*)(&stage[g * 256]),
            16, 0, 0);
    }

    // ---- PHASE 1b: DMA xp tile (60 planes x 256 px; 1KB contiguous each) ----
    {
        const float* xpb = xp + ((size_t)(n * kP * kHD) << 14) + yA * kH;
        for (int s = wv; s < kP * kHD; s += 4) {
            const float* gp = xpb + ((size_t)s << 14) + l * 4;
            __builtin_amdgcn_global_load_lds(
                (const __attribute__((address_space(1))) void*)gp,
                (__attribute__((address_space(3))) void*)(&xpl[s * 256]),
                16, 0, 0);
        }
    }

    __syncthreads();   // single drain for ALL input traffic

    const int ly = threadIdx.x >> 7;
    const int xc = threadIdx.x & (kH - 1);
    const int yc = yA + ly;
    const int pxbase = ly * kH + xc;          // 0..255 within xp tile

    // ---- bilinear coords ----
    const float py = (float)yc * scale;
    int y0 = (int)py; y0 = y0 > (kHin - 2) ? (kHin - 2) : y0;
    const float fy = py - (float)y0;
    const int d0 = y0 - ry0;
    const float pxf_ = (float)xc * scale;
    int x0 = (int)pxf_; x0 = x0 > (kHin - 2) ? (kHin - 2) : x0;
    const float fx = pxf_ - (float)x0;
    const float w00 = (1.0f - fy) * (1.0f - fx);
    const float w01 = (1.0f - fy) * fx;
    const float w10 = fy * (1.0f - fx);
    const float w11 = fy * fx;

    // ---- windows from LDS -> packed half2 ----
    half2v xh0v2[5], xh1v2[5], xfv2[5];
    const int sx = xc >> 1;
    #pragma unroll
    for (int j = 0; j < 5; ++j) {
        float v[2], u[2], f[2];
        #pragma unroll
        for (int t = 0; t < 2; ++t) {
            const int c = 2 * j + t;
            const float* r0 = &stage[(c * 3 + d0) * kHin];
            v[t] = r0[x0] * w00 + r0[x0 + 1] * w01 +
                   r0[kHin + x0] * w10 + r0[kHin + x0 + 1] * w11;
            const float* r1 = &stage[(30 + c * 3 + d0) * kHin];
            u[t] = r1[x0] * w00 + r1[x0 + 1] * w01 +
                   r1[kHin + x0] * w10 + r1[kHin + x0 + 1] * w11;
            f[t] = stage[(60 + c) * kHin + sx];
        }
        xh0v2[j] = pk(v[0], v[1]);
        xh1v2[j] = pk(u[0], u[1]);
        xfv2[j]  = pk(f[0], f[1]);
    }

    // ---- xp from LDS -> packed half2 ----
    half2v xpv2[kP][5];
    #pragma unroll
    for (int p = 0; p < kP; ++p)
        #pragma unroll
        for (int j = 0; j < 5; ++j) {
            const float lo = xpl[(p * kHD + 2 * j)     * 256 + pxbase];
            const float hi = xpl[(p * kHD + 2 * j + 1) * 256 + pxbase];
            xpv2[p][j] = pk(lo, hi);
        }

    // ---- attentions via fdot2 ----
    float attf[kP], atth[kP], dpa[kP];
    #pragma unroll
    for (int p = 0; p < kP; ++p) {
        float af = bfb[p], ah = bhb[p], ad = batt[p];
        #pragma unroll
        for (int j = 0; j < 5; ++j) {
            const half2v xh2 = (p < 4) ? xh0v2[j] : xh1v2[j];
            af = dot2(xfv2[j],    w2[WF2 + p * 10 + j],     af);
            af = dot2(xpv2[p][j], w2[WF2 + p * 10 + 5 + j], af);
            ah = dot2(xh2,        w2[WH2 + p * 10 + j],     ah);
            ah = dot2(xpv2[p][j], w2[WH2 + p * 10 + 5 + j], ah);
            ad = dot2(xpv2[p][j], w2[WATT2 + p * 5 + j],    ad);
        }
        attf[p] = sigm(af);
        atth[p] = sigm(ah);
        dpa[p]  = sigm(ad);
    }

    const size_t pixoff = (size_t)yc * kH + xc;
    #pragma unroll
    for (int p = 0; p < kP; ++p) {
        const float ap = (attf[p] + atth[p] + dpa[p]) * (1.0f / 3.0f);
        out_att[(size_t)(n * kP + p) * (kH * kH) + pixoff] = ap;
    }

    // ---- edge messages via fdot2 ----
    float xpp[kP][kHD];
    #pragma unroll
    for (int p = 0; p < kP; ++p)
        #pragma unroll
        for (int c = 0; c < kHD; ++c) xpp[p][c] = 0.0f;

    constexpr int EA[kNE] = {0, 1, 2, 1, 4};
    constexpr int EB[kNE] = {1, 2, 3, 4, 5};
    #pragma unroll
    for (int e = 0; e < kNE; ++e) {
        const int a = EA[e], b = EB[e];
        const float sa = 2.0f - dpa[a];
        const float sb = 2.0f - dpa[b];
        #pragma unroll
        for (int d = 0; d < kHD; ++d) {
            float t = 0.0f;
            #pragma unroll
            for (int j = 0; j < 5; ++j) {
                t = dot2(xpv2[a][j], w2[WDP2 + (e * 10 + d) * 10 + j],     t);
                t = dot2(xpv2[b][j], w2[WDP2 + (e * 10 + d) * 10 + 5 + j], t);
            }
            t = fmaxf(t, 0.0f);
            xpp[b][d] += t * sa;
            xpp[a][d] += t * sb;
        }
    }
    half2v xpp2[kP][5];
    #pragma unroll
    for (int p = 0; p < kP; ++p)
        #pragma unroll
        for (int j = 0; j < 5; ++j)
            xpp2[p][j] = pk(xpp[p][2 * j], xpp[p][2 * j + 1]);

    // ---- update via fdot2 + stores ----
    #pragma unroll
    for (int p = 0; p < kP; ++p) {
        #pragma unroll
        for (int d = 0; d < kHD; ++d) {
            const int wb = WUP2 + (p * 10 + d) * 20;
            float a1 = 0.0f, a2 = 0.0f, a3 = 0.0f, a4 = 0.0f;
            #pragma unroll
            for (int j = 0; j < 5; ++j) {
                const half2v xh2 = (p < 4) ? xh0v2[j] : xh1v2[j];
                a1 = dot2(xpv2[p][j], w2[wb + j],      a1);
                a2 = dot2(xfv2[j],    w2[wb + 5 + j],  a2);
                a3 = dot2(xh2,        w2[wb + 10 + j], a3);
                a4 = dot2(xpp2[p][j], w2[wb + 15 + j], a4);
            }
            float upd = a1 + attf[p] * a2 + atth[p] * a3 + a4;
            upd = fmaxf(upd, 0.0f);
            const float xpd = xpl[(p * kHD + d) * 256 + pxbase];
            const float o = fmaxf(xpd + upd, 0.0f);
            out_xp[(size_t)(n * kP * kHD + p * kHD + d) * (kH * kH) + pixoff] = o;
        }
    }
}

extern "C" void kernel_launch(void* const* d_in, const int* in_sizes, int n_in,
                              void* d_out, int out_size, void* d_ws, size_t ws_size,
                              hipStream_t stream) {
    const float* xf   = (const float*)d_in[0];
    const float* xh0  = (const float*)d_in[1];
    const float* xh1  = (const float*)d_in[2];
    const float* xp   = (const float*)d_in[3];
    const float* Wf   = (const float*)d_in[4];
    const float* bfb  = (const float*)d_in[5];
    const float* Wh   = (const float*)d_in[6];
    const float* bhb  = (const float*)d_in[7];
    const float* Watt = (const float*)d_in[8];
    const float* batt = (const float*)d_in[9];
    const float* Wdp  = (const float*)d_in[10];
    const float* Wup  = (const float*)d_in[11];

    int N = out_size / ((kP * kHD + kP) * kH * kH);
    if (N <= 0) N = 32;
    const int npix = N * kH * kH;

    float* out_xp  = (float*)d_out;
    float* out_att = out_xp + (size_t)N * kP * kHD * kH * kH;
    half2v* w2 = (half2v*)d_ws;

    prepack_weights<<<(NPAIR + 255) / 256, 256, 0, stream>>>(
        Wf, Wh, Watt, Wdp, Wup, w2);

    const int block = 256;
    const int grid = npix / block;
    Part_Graph_51539607552364_kernel<<<grid, block, 0, stream>>>(
        xf, xh0, xh1, xp, w2, bfb, bhb, batt, out_xp, out_att);
}